// Round 4
// baseline (296.036 us; speedup 1.0000x reference)
//
#include <hip/hip_runtime.h>

// Problem: B=32, NC=4, H=512, W=512, fp32 in, two fp32 scalars out.
// lseg = mean BCE-with-logits; liou = 1 - mean_b( sum_c IoU(b,c) / present(b) ).
//
// R3 post-mortem: speed ~ resident_waves x loads_in_flight_per_wave. R2 had
// waves but not MLP; R3 had MLP but halved waves. R4: both — launch_bounds
// (256,8) forces VGPR<=64 (8 waves/SIMD, 32/CU with the 2048-block grid),
// 8-load group per iter pinned by sched_barrier, counters packed into 8-bit
// fields to fit the register budget, bce atomics sharded per batch.

#define NB   32
#define NCL  4
constexpr int HW      = 512 * 512;       // 262144 pixels per (b,c) plane
constexpr int GROUPS  = HW / 4;          // 65536 float4-groups per batch
constexpr int THREADS = 256;
constexpr int BLOCKS_PER_BATCH = 64;
constexpr int TPB = BLOCKS_PER_BATCH * THREADS;   // 16384 threads per batch
constexpr int ITERS = GROUPS / TPB;               // 4 groups (16 pixels) per thread

__global__ __launch_bounds__(THREADS, 8)   // force VGPR<=64: 8 waves/SIMD
void seg_main(const float* __restrict__ pred,
              const float* __restrict__ tgt,
              float* __restrict__ bce_shard,  // [NB] per-batch BCE partials
              unsigned* __restrict__ pc_g,    // [NB][NCL] pred counts
              unsigned* __restrict__ tc_g,    // [NB][NCL] tgt counts
              unsigned* __restrict__ tp_g)    // [NB][NCL] true positives
{
    const int b     = blockIdx.x & (NB - 1);       // one batch per block
    const int chunk = blockIdx.x >> 5;             // 0..63
    const int tib   = chunk * THREADS + threadIdx.x;
    const size_t base = (size_t)b * NCL * HW + 4u * (size_t)tib;

    float bce = 0.0f;
    // 12 counters packed as 8-bit fields (max 16 per field at ITERS=4)
    unsigned pcP = 0, tcP = 0, tpP = 0;

#pragma unroll 1
    for (int it = 0; it < ITERS; ++it) {
        const size_t off = base + (size_t)it * 4u * TPB;
        float4 pv[NCL], tv[NCL];
#pragma unroll
        for (int c = 0; c < NCL; ++c) {
            pv[c] = *reinterpret_cast<const float4*>(pred + off + (size_t)c * HW);
            tv[c] = *reinterpret_cast<const float4*>(tgt  + off + (size_t)c * HW);
        }
        // all 8 loads issue before any vmcnt wait / compute
        __builtin_amdgcn_sched_barrier(0);
#pragma unroll
        for (int j = 0; j < 4; ++j) {
            float pj[NCL], tj[NCL];
#pragma unroll
            for (int c = 0; c < NCL; ++c) {
                pj[c] = (&pv[c].x)[j];
                tj[c] = (&tv[c].x)[j];
            }
            // first-occurrence argmax (strict >) matches jnp.argmax
            int cp = 0, ct = 0;
            float bp = pj[0], bt = tj[0];
#pragma unroll
            for (int c = 1; c < NCL; ++c) {
                if (pj[c] > bp) { bp = pj[c]; cp = c; }
                if (tj[c] > bt) { bt = tj[c]; ct = c; }
            }
            pcP += 1u << (8 * cp);
            tcP += 1u << (8 * ct);
            tpP += (cp == ct) ? (1u << (8 * cp)) : 0u;
            // BCE with logits, numerically stable
#pragma unroll
            for (int c = 0; c < NCL; ++c) {
                const float p = pj[c];
                bce += fmaxf(p, 0.0f) - p * tj[c]
                     + __logf(1.0f + __expf(-fabsf(p)));
            }
        }
    }

    // widen 8-bit fields -> 16-bit fields in u64 (wave sum <= 1024 per field)
    unsigned long long P = 0, T = 0, Q = 0;
#pragma unroll
    for (int c = 0; c < NCL; ++c) {
        P |= (unsigned long long)((pcP >> (8 * c)) & 0xFFu) << (16 * c);
        T |= (unsigned long long)((tcP >> (8 * c)) & 0xFFu) << (16 * c);
        Q |= (unsigned long long)((tpP >> (8 * c)) & 0xFFu) << (16 * c);
    }
#pragma unroll
    for (int o = 32; o > 0; o >>= 1) {
        bce += __shfl_xor(bce, o);
        P   += __shfl_xor(P, o);
        T   += __shfl_xor(T, o);
        Q   += __shfl_xor(Q, o);
    }
    if ((threadIdx.x & 63) == 0) {
        atomicAdd(&bce_shard[b], bce);     // 256 atomics per shard
#pragma unroll
        for (int c = 0; c < NCL; ++c) {
            atomicAdd(&pc_g[b * NCL + c], (unsigned)((P >> (16 * c)) & 0xFFFFu));
            atomicAdd(&tc_g[b * NCL + c], (unsigned)((T >> (16 * c)) & 0xFFFFu));
            atomicAdd(&tp_g[b * NCL + c], (unsigned)((Q >> (16 * c)) & 0xFFFFu));
        }
    }
}

__global__ void seg_final(const float* __restrict__ bce_shard,
                          const unsigned* __restrict__ pc_g,
                          const unsigned* __restrict__ tc_g,
                          const unsigned* __restrict__ tp_g,
                          float* __restrict__ out)
{
    const int t = threadIdx.x;
    float bce = 0.0f, val = 0.0f;
    if (t < NB) {
        bce = bce_shard[t];
        float iou = 0.0f;
        int present = 0;
#pragma unroll
        for (int c = 0; c < NCL; ++c) {
            const float P = (float)pc_g[t * NCL + c];
            const float T = (float)tc_g[t * NCL + c];
            const float K = (float)tp_g[t * NCL + c];
            const float den = P + T - K;
            if (den > 0.0f) iou += K / den;
            present += (tc_g[t * NCL + c] > 0u);
        }
        val = iou / (float)present;   // present >= 1 always (sum_c tgt_cnt = HW)
    }
#pragma unroll
    for (int o = 32; o > 0; o >>= 1) {
        bce += __shfl_xor(bce, o);
        val += __shfl_xor(val, o);
    }
    if (t == 0) {
        out[0] = bce / (float)((size_t)NB * NCL * HW);  // lseg
        out[1] = 1.0f - val / (float)NB;                // liou
    }
}

extern "C" void kernel_launch(void* const* d_in, const int* in_sizes, int n_in,
                              void* d_out, int out_size, void* d_ws, size_t ws_size,
                              hipStream_t stream) {
    const float* pred = (const float*)d_in[0];
    const float* tgt  = (const float*)d_in[1];
    float* out = (float*)d_out;

    // workspace: [0,128): 32 bce shards; [256, 256+1536): 3 x 128 uint counters
    float*    bce_shard = (float*)d_ws;
    unsigned* pc_g      = (unsigned*)((char*)d_ws + 256);
    unsigned* tc_g      = pc_g + NB * NCL;
    unsigned* tp_g      = tc_g + NB * NCL;

    hipMemsetAsync(d_ws, 0, 256 + 3 * NB * NCL * sizeof(unsigned), stream);
    seg_main<<<NB * BLOCKS_PER_BATCH, THREADS, 0, stream>>>(pred, tgt, bce_shard,
                                                            pc_g, tc_g, tp_g);
    seg_final<<<1, 64, 0, stream>>>(bce_shard, pc_g, tc_g, tp_g, out);
}

// Round 5
// 293.736 us; speedup vs baseline: 1.0078x; 1.0078x over previous
//
#include <hip/hip_runtime.h>

// Problem: B=32, NC=4, H=512, W=512, fp32 in, two fp32 scalars out.
// lseg = mean BCE-with-logits; liou = 1 - mean_b( sum_c IoU(b,c) / present(b) ).
//
// R4 post-mortem: compiler pinned VGPR=32 regardless of launch_bounds ->
// ~4 loads in flight/wave -> 1.93 TB/s latency-bound (R3's 100% L3-hit replay
// at identical dur proves latency, not BW, is the wall).
// R5: inline-asm global_load_dwordx4 + asm s_waitcnt vmcnt(8/0) tied to the
// consumed buffer via "+v". Compiler can't see/serialize these loads.
// Double-buffered: 16 loads in flight per wave at steady state.

#define NB   32
#define NCL  4
constexpr int HW      = 512 * 512;       // 262144 pixels per (b,c) plane
constexpr int GROUPS  = HW / 4;          // 65536 float4-groups per batch
constexpr int THREADS = 256;
constexpr int BLOCKS_PER_BATCH = 64;
constexpr int TPB = BLOCKS_PER_BATCH * THREADS;   // 16384 threads per batch
constexpr int ITERS = GROUPS / TPB;               // 4 groups (16 pixels) per thread

typedef float v4f __attribute__((ext_vector_type(4)));

__device__ __forceinline__ void gload(v4f& d, unsigned voff_bytes, const float* base) {
    // d <- mem[base + voff_bytes]; compiler does NOT track this load's vmcnt.
    asm volatile("global_load_dwordx4 %0, %1, %2"
                 : "=v"(d) : "v"(voff_bytes), "s"(base));
}

// issue one 8-load group (4 pred planes + 4 tgt planes)
#define ISSUE(BUF, VOFF)                                                    \
    do {                                                                    \
        gload((BUF)[0], (VOFF), base[0]); gload((BUF)[1], (VOFF), base[1]); \
        gload((BUF)[2], (VOFF), base[2]); gload((BUF)[3], (VOFF), base[3]); \
        gload((BUF)[4], (VOFF), base[4]); gload((BUF)[5], (VOFF), base[5]); \
        gload((BUF)[6], (VOFF), base[6]); gload((BUF)[7], (VOFF), base[7]); \
    } while (0)

// s_waitcnt vmcnt(N) with the waited buffer tied through the asm, so no
// consumer can be scheduled above it. N is a literal string.
#define WAIT_TIE(NSTR, BUF)                                                  \
    asm volatile("s_waitcnt vmcnt(" NSTR ")"                                 \
                 : "+v"((BUF)[0]), "+v"((BUF)[1]), "+v"((BUF)[2]),           \
                   "+v"((BUF)[3]), "+v"((BUF)[4]), "+v"((BUF)[5]),           \
                   "+v"((BUF)[6]), "+v"((BUF)[7]))

__global__ __launch_bounds__(THREADS, 5)   // cap 102 VGPR: 64 payload + overhead
void seg_main(const float* __restrict__ pred,
              const float* __restrict__ tgt,
              float* __restrict__ bce_shard,  // [NB] per-batch BCE partials
              unsigned* __restrict__ pc_g,    // [NB][NCL] pred counts
              unsigned* __restrict__ tc_g,    // [NB][NCL] tgt counts
              unsigned* __restrict__ tp_g)    // [NB][NCL] true positives
{
    const int b     = blockIdx.x & (NB - 1);       // one batch per block (uniform)
    const int chunk = blockIdx.x >> 5;             // 0..63
    const int tib   = chunk * THREADS + threadIdx.x;

    // 8 wave-uniform plane base pointers -> SGPR pairs via "s" constraint
    const float* base[8];
    {
        const size_t boff = (size_t)b * NCL * HW;
#pragma unroll
        for (int c = 0; c < NCL; ++c) {
            base[c]     = pred + boff + (size_t)c * HW;
            base[4 + c] = tgt  + boff + (size_t)c * HW;
        }
    }

    float bce = 0.0f;
    unsigned pcP = 0, tcP = 0, tpP = 0;   // 12 counters, 8-bit fields (max 16)

    v4f buf[2][8];
    ISSUE(buf[0], 16u * (unsigned)tib);

#pragma unroll
    for (int it = 0; it < ITERS; ++it) {
        const int cur = it & 1;
        const int nxt = cur ^ 1;
        if (it + 1 < ITERS)
            ISSUE(buf[nxt], 16u * (unsigned)(tib + (it + 1) * TPB));
        // wait for the 8 OLDEST loads (= buf[cur]); leave prefetch in flight
        if (it + 1 < ITERS) { WAIT_TIE("8", buf[cur]); }
        else                { WAIT_TIE("0", buf[cur]); }

#pragma unroll
        for (int j = 0; j < 4; ++j) {
            float pj[NCL], tj[NCL];
#pragma unroll
            for (int c = 0; c < NCL; ++c) {
                pj[c] = buf[cur][c][j];
                tj[c] = buf[cur][4 + c][j];
            }
            // first-occurrence argmax (strict >) matches jnp.argmax
            int cp = 0, ct = 0;
            float bp = pj[0], bt = tj[0];
#pragma unroll
            for (int c = 1; c < NCL; ++c) {
                if (pj[c] > bp) { bp = pj[c]; cp = c; }
                if (tj[c] > bt) { bt = tj[c]; ct = c; }
            }
            pcP += 1u << (8 * cp);
            tcP += 1u << (8 * ct);
            tpP += (cp == ct) ? (1u << (8 * cp)) : 0u;
            // BCE with logits, numerically stable
#pragma unroll
            for (int c = 0; c < NCL; ++c) {
                const float p = pj[c];
                bce += fmaxf(p, 0.0f) - p * tj[c]
                     + __logf(1.0f + __expf(-fabsf(p)));
            }
        }
    }

    // widen 8-bit fields -> 16-bit fields in u64 (wave sum <= 1024 per field)
    unsigned long long P = 0, T = 0, Q = 0;
#pragma unroll
    for (int c = 0; c < NCL; ++c) {
        P |= (unsigned long long)((pcP >> (8 * c)) & 0xFFu) << (16 * c);
        T |= (unsigned long long)((tcP >> (8 * c)) & 0xFFu) << (16 * c);
        Q |= (unsigned long long)((tpP >> (8 * c)) & 0xFFu) << (16 * c);
    }
#pragma unroll
    for (int o = 32; o > 0; o >>= 1) {
        bce += __shfl_xor(bce, o);
        P   += __shfl_xor(P, o);
        T   += __shfl_xor(T, o);
        Q   += __shfl_xor(Q, o);
    }
    if ((threadIdx.x & 63) == 0) {
        atomicAdd(&bce_shard[b], bce);     // 256 atomics per shard
#pragma unroll
        for (int c = 0; c < NCL; ++c) {
            atomicAdd(&pc_g[b * NCL + c], (unsigned)((P >> (16 * c)) & 0xFFFFu));
            atomicAdd(&tc_g[b * NCL + c], (unsigned)((T >> (16 * c)) & 0xFFFFu));
            atomicAdd(&tp_g[b * NCL + c], (unsigned)((Q >> (16 * c)) & 0xFFFFu));
        }
    }
}

__global__ void seg_final(const float* __restrict__ bce_shard,
                          const unsigned* __restrict__ pc_g,
                          const unsigned* __restrict__ tc_g,
                          const unsigned* __restrict__ tp_g,
                          float* __restrict__ out)
{
    const int t = threadIdx.x;
    float bce = 0.0f, val = 0.0f;
    if (t < NB) {
        bce = bce_shard[t];
        float iou = 0.0f;
        int present = 0;
#pragma unroll
        for (int c = 0; c < NCL; ++c) {
            const float P = (float)pc_g[t * NCL + c];
            const float T = (float)tc_g[t * NCL + c];
            const float K = (float)tp_g[t * NCL + c];
            const float den = P + T - K;
            if (den > 0.0f) iou += K / den;
            present += (tc_g[t * NCL + c] > 0u);
        }
        val = iou / (float)present;   // present >= 1 always (sum_c tgt_cnt = HW)
    }
#pragma unroll
    for (int o = 32; o > 0; o >>= 1) {
        bce += __shfl_xor(bce, o);
        val += __shfl_xor(val, o);
    }
    if (t == 0) {
        out[0] = bce / (float)((size_t)NB * NCL * HW);  // lseg
        out[1] = 1.0f - val / (float)NB;                // liou
    }
}

extern "C" void kernel_launch(void* const* d_in, const int* in_sizes, int n_in,
                              void* d_out, int out_size, void* d_ws, size_t ws_size,
                              hipStream_t stream) {
    const float* pred = (const float*)d_in[0];
    const float* tgt  = (const float*)d_in[1];
    float* out = (float*)d_out;

    // workspace: [0,128): 32 bce shards; [256, 256+1536): 3 x 128 uint counters
    float*    bce_shard = (float*)d_ws;
    unsigned* pc_g      = (unsigned*)((char*)d_ws + 256);
    unsigned* tc_g      = pc_g + NB * NCL;
    unsigned* tp_g      = tc_g + NB * NCL;

    hipMemsetAsync(d_ws, 0, 256 + 3 * NB * NCL * sizeof(unsigned), stream);
    seg_main<<<NB * BLOCKS_PER_BATCH, THREADS, 0, stream>>>(pred, tgt, bce_shard,
                                                            pc_g, tc_g, tp_g);
    seg_final<<<1, 64, 0, stream>>>(bce_shard, pc_g, tc_g, tp_g, out);
}

// Round 6
// 288.315 us; speedup vs baseline: 1.0268x; 1.0188x over previous
//
#include <hip/hip_runtime.h>

// Problem: B=32, NC=4, H=512, W=512, fp32 in, two fp32 scalars out.
// lseg = mean BCE-with-logits; liou = 1 - mean_b( sum_c IoU(b,c) / present(b) ).
//
// R5 post-mortem: VGPR-staged pipelines cap at waves*depth*16B ~ 3.3 KB in
// flight/CU (all of R1-R5 sit on that iso-curve). R6 removes the constraint:
// global_load_lds width=16 stages 1 KB/wave-instruction into LDS with zero
// payload VGPRs. 8-instruction slot = 8 KB per wave per latency window.
// Ring-2 slots, wave-private (no __syncthreads). Order: wait vmcnt(0) ->
// ds_read slot -> issue next slot -> compute, so compiler-inserted waits are
// redundant, and prefetch overlaps the ~600cyc compute.

#define NB   32
#define NCL  4
constexpr int HW      = 512 * 512;       // 262144 pixels per (b,c) plane
constexpr int GROUPS  = HW / 4;          // 65536 float4-groups per batch
constexpr int THREADS = 256;
constexpr int WPB     = THREADS / 64;    // 4 waves/block
constexpr int BLOCKS_PER_BATCH = 16;
constexpr int NBLOCKS = NB * BLOCKS_PER_BATCH;              // 512 = 2 blocks/CU
constexpr int SLOTS   = GROUPS / (BLOCKS_PER_BATCH * WPB * 64);  // 16 slots/wave

typedef float v4f __attribute__((ext_vector_type(4)));
typedef const __attribute__((address_space(1))) void gvoid_t;
typedef __attribute__((address_space(3))) void svoid_t;

__global__ __launch_bounds__(THREADS, 2)
void seg_main(const float* __restrict__ pred,
              const float* __restrict__ tgt,
              float* __restrict__ bce_shard,  // [NB] per-batch BCE partials
              unsigned* __restrict__ pc_g,    // [NB][NCL] pred counts
              unsigned* __restrict__ tc_g,    // [NB][NCL] tgt counts
              unsigned* __restrict__ tp_g)    // [NB][NCL] true positives
{
    // 4 waves x ring-2 x 8 planes x 64 lanes x 16 B = 64 KB (2 blocks/CU)
    __shared__ v4f stage[WPB][2][8][64];

    const int b    = blockIdx.x & (NB - 1);
    const int bib  = blockIdx.x >> 5;            // 0..15 block-in-batch
    const int wid  = threadIdx.x >> 6;
    const int lane = threadIdx.x & 63;

    const float* base[8];
    {
        const size_t boff = (size_t)b * NCL * HW;
#pragma unroll
        for (int c = 0; c < NCL; ++c) {
            base[c]     = pred + boff + (size_t)c * HW;
            base[4 + c] = tgt  + boff + (size_t)c * HW;
        }
    }

    // this wave's first float4-group; each slot covers 64 groups (1/lane)
    const int wgoff = (bib * WPB + wid) * (SLOTS * 64);

    float bce = 0.0f;
    unsigned pcP = 0, tcP = 0, tpP = 0;   // 12 counters, 8-bit fields (max 64)

    // issue one slot: 8 x (1 KB direct-to-LDS), zero payload VGPRs
#define ISSUE_SLOT(S, RING)                                                   \
    do {                                                                      \
        const size_t g0 = (size_t)(wgoff + (S) * 64 + lane) * 4u;             \
        _Pragma("unroll")                                                     \
        for (int p = 0; p < 8; ++p) {                                         \
            __builtin_amdgcn_global_load_lds(                                 \
                (gvoid_t*)(base[p] + g0),                                     \
                (svoid_t*)&stage[wid][RING][p][0], 16, 0, 0);                 \
        }                                                                     \
    } while (0)

    ISSUE_SLOT(0, 0);

#pragma unroll 1
    for (int s = 0; s < SLOTS; ++s) {
        const int ring = s & 1;
        // slot s's 8 loads are the only outstanding vmem -> drain them
        asm volatile("s_waitcnt vmcnt(0)" ::: "memory");

        v4f pv[NCL], tv[NCL];
#pragma unroll
        for (int c = 0; c < NCL; ++c) {
            pv[c] = stage[wid][ring][c][lane];      // ds_read_b128, conflict-free
            tv[c] = stage[wid][ring][4 + c][lane];
        }
        // prefetch next slot NOW; it flies during the compute below
        if (s + 1 < SLOTS) ISSUE_SLOT(s + 1, ring ^ 1);

#pragma unroll
        for (int j = 0; j < 4; ++j) {
            float pj[NCL], tj[NCL];
#pragma unroll
            for (int c = 0; c < NCL; ++c) {
                pj[c] = pv[c][j];
                tj[c] = tv[c][j];
            }
            // first-occurrence argmax (strict >) matches jnp.argmax
            int cp = 0, ct = 0;
            float bp = pj[0], bt = tj[0];
#pragma unroll
            for (int c = 1; c < NCL; ++c) {
                if (pj[c] > bp) { bp = pj[c]; cp = c; }
                if (tj[c] > bt) { bt = tj[c]; ct = c; }
            }
            pcP += 1u << (8 * cp);
            tcP += 1u << (8 * ct);
            tpP += (cp == ct) ? (1u << (8 * cp)) : 0u;
            // BCE with logits, numerically stable
#pragma unroll
            for (int c = 0; c < NCL; ++c) {
                const float p = pj[c];
                bce += fmaxf(p, 0.0f) - p * tj[c]
                     + __logf(1.0f + __expf(-fabsf(p)));
            }
        }
    }
#undef ISSUE_SLOT

    // widen 8-bit fields -> 16-bit fields in u64 (wave sum <= 4096 per field)
    unsigned long long P = 0, T = 0, Q = 0;
#pragma unroll
    for (int c = 0; c < NCL; ++c) {
        P |= (unsigned long long)((pcP >> (8 * c)) & 0xFFu) << (16 * c);
        T |= (unsigned long long)((tcP >> (8 * c)) & 0xFFu) << (16 * c);
        Q |= (unsigned long long)((tpP >> (8 * c)) & 0xFFu) << (16 * c);
    }
#pragma unroll
    for (int o = 32; o > 0; o >>= 1) {
        bce += __shfl_xor(bce, o);
        P   += __shfl_xor(P, o);
        T   += __shfl_xor(T, o);
        Q   += __shfl_xor(Q, o);
    }
    if ((threadIdx.x & 63) == 0) {
        atomicAdd(&bce_shard[b], bce);     // 64 atomics per shard
#pragma unroll
        for (int c = 0; c < NCL; ++c) {
            atomicAdd(&pc_g[b * NCL + c], (unsigned)((P >> (16 * c)) & 0xFFFFu));
            atomicAdd(&tc_g[b * NCL + c], (unsigned)((T >> (16 * c)) & 0xFFFFu));
            atomicAdd(&tp_g[b * NCL + c], (unsigned)((Q >> (16 * c)) & 0xFFFFu));
        }
    }
}

__global__ void seg_final(const float* __restrict__ bce_shard,
                          const unsigned* __restrict__ pc_g,
                          const unsigned* __restrict__ tc_g,
                          const unsigned* __restrict__ tp_g,
                          float* __restrict__ out)
{
    const int t = threadIdx.x;
    float bce = 0.0f, val = 0.0f;
    if (t < NB) {
        bce = bce_shard[t];
        float iou = 0.0f;
        int present = 0;
#pragma unroll
        for (int c = 0; c < NCL; ++c) {
            const float P = (float)pc_g[t * NCL + c];
            const float T = (float)tc_g[t * NCL + c];
            const float K = (float)tp_g[t * NCL + c];
            const float den = P + T - K;
            if (den > 0.0f) iou += K / den;
            present += (tc_g[t * NCL + c] > 0u);
        }
        val = iou / (float)present;   // present >= 1 always (sum_c tgt_cnt = HW)
    }
#pragma unroll
    for (int o = 32; o > 0; o >>= 1) {
        bce += __shfl_xor(bce, o);
        val += __shfl_xor(val, o);
    }
    if (t == 0) {
        out[0] = bce / (float)((size_t)NB * NCL * HW);  // lseg
        out[1] = 1.0f - val / (float)NB;                // liou
    }
}

extern "C" void kernel_launch(void* const* d_in, const int* in_sizes, int n_in,
                              void* d_out, int out_size, void* d_ws, size_t ws_size,
                              hipStream_t stream) {
    const float* pred = (const float*)d_in[0];
    const float* tgt  = (const float*)d_in[1];
    float* out = (float*)d_out;

    // workspace: [0,128): 32 bce shards; [256, 256+1536): 3 x 128 uint counters
    float*    bce_shard = (float*)d_ws;
    unsigned* pc_g      = (unsigned*)((char*)d_ws + 256);
    unsigned* tc_g      = pc_g + NB * NCL;
    unsigned* tp_g      = tc_g + NB * NCL;

    hipMemsetAsync(d_ws, 0, 256 + 3 * NB * NCL * sizeof(unsigned), stream);
    seg_main<<<NBLOCKS, THREADS, 0, stream>>>(pred, tgt, bce_shard,
                                              pc_g, tc_g, tp_g);
    seg_final<<<1, 64, 0, stream>>>(bce_shard, pc_g, tc_g, tp_g, out);
}